// Round 15
// baseline (25.993 us; speedup 1.0000x reference)
//
#include <hip/hip_runtime.h>
#include <stdint.h>

#define IN_F 512
#define OUT_F 768
#define BD 256
#define ID 16
#define ND 256
#define CD 4096   // B*I columns in T

#define QSCALE 42.5f   // u8 step: range [-3,3] -> [0,255]; max SAD 4080 < 4096

typedef __bf16 bf16x8 __attribute__((ext_vector_type(8)));
typedef float f32x4 __attribute__((ext_vector_type(4)));

__device__ __forceinline__ unsigned short f2bf(float f) {
    union { float f; uint32_t u; } v; v.f = f;
    uint32_t u = v.u + 0x7FFFu + ((v.u >> 16) & 1u);  // RNE
    return (unsigned short)(u >> 16);
}

// v_sad_u8: D = sum_{k=0..3} |a.u8[k] - b.u8[k]| + c   (one full-rate VALU op)
__device__ __forceinline__ unsigned sad8(unsigned a, unsigned b, unsigned c) {
    unsigned d;
    asm("v_sad_u8 %0, %1, %2, %3" : "=v"(d) : "v"(a), "v"(b), "v"(c));
    return d;
}

// ---- single kernel: one block per b, 1024 threads (16 waves, 4/SIMD) ----
// stage T slice -> LDS f32 -> bf16 B-fragments; A converted from f32 x on
// the fly (R12-proven); MFMA 16x16x32; u8 quantize; SAD+LUT pair phase;
// 16-way reduce; concat copy. No workspace, no second kernel.
__global__ __launch_bounds__(1024) void mbd_all(const float* __restrict__ x,
                                                const float* __restrict__ T,
                                                float* __restrict__ out) {
    __shared__ __align__(16) unsigned char smem[32768 + 16384 + 4096];  // 52 KB
    float* Tst = (float*)smem;                                 // 32 KB staging
    float* LUT = (float*)smem;                                 // floats [0,4096) (16 KB)
    float* red = (float*)smem + 4096;                          // next 16 KB
    unsigned short* Tfrag = (unsigned short*)(smem + 32768);   // 16 KB
    unsigned char* Mq = smem + 32768 + 16384;                  // u8[256][16], 4 KB

    const int b = blockIdx.x;
    const int t = threadIdx.x;
    const int lane = t & 63;
    const int w = t >> 6;
    const int rc = lane & 15;  // A-row in tile == B col (i) == D col
    const int g = lane >> 4;   // k-group

    // ---- stage T[:, b*16..+16) (512 x 16 f32 = 32 KB), coalesced ----
#pragma unroll
    for (int s = 0; s < 2; ++s) {
        int q = s * 1024 + t;
        int f = q >> 2, c4 = (q & 3) << 2;
        float4 v = *reinterpret_cast<const float4*>(T + (size_t)f * CD + b * ID + c4);
        *reinterpret_cast<float4*>(&Tst[f * ID + c4]) = v;
    }
    __syncthreads();

    // ---- convert: Tfrag[kg*128 + c*8 + e] = bf16(Tst[(kg*8+e)*16 + c]) ----
    {
        const int kg = t >> 4;
        const int c = t & 15;
        union { unsigned short s[8]; uint4 v; } p;
#pragma unroll
        for (int e = 0; e < 8; ++e) p.s[e] = f2bf(Tst[(kg * 8 + e) * ID + c]);
        *reinterpret_cast<uint4*>(Tfrag + (size_t)t * 8) = p.v;
    }
    __syncthreads();  // Tst dead from here; LUT overwrites it

    // ---- build exp LUT: LUT[s] = exp2(s * -log2e/QSCALE), s in [0,4096) ----
    {
        const float K = -1.44269504f / QSCALE;
#pragma unroll
        for (int u = 0; u < 4; ++u) {
            int idx = t * 4 + u;
            LUT[idx] = exp2f((float)idx * K);
        }
    }

    // ---- phase G: wave w -> n-tile w; A from f32 x on the fly (R12-proven) ----
    const bf16x8* Bf = reinterpret_cast<const bf16x8*>(Tfrag);
    const float* xw = x + (size_t)(w * 16 + rc) * IN_F;
    f32x4 acc = {0.f, 0.f, 0.f, 0.f};
#pragma unroll 4
    for (int k = 0; k < 16; ++k) {
        float4 xa = *reinterpret_cast<const float4*>(xw + k * 32 + g * 8);
        float4 xb = *reinterpret_cast<const float4*>(xw + k * 32 + g * 8 + 4);
        bf16x8 afr;
        afr[0] = (__bf16)xa.x; afr[1] = (__bf16)xa.y;
        afr[2] = (__bf16)xa.z; afr[3] = (__bf16)xa.w;
        afr[4] = (__bf16)xb.x; afr[5] = (__bf16)xb.y;
        afr[6] = (__bf16)xb.z; afr[7] = (__bf16)xb.w;
        bf16x8 bfr = Bf[(k * 4 + g) * 16 + rc];  // contiguous b128, conflict-free
        acc = __builtin_amdgcn_mfma_f32_16x16x32_bf16(afr, bfr, acc, 0, 0, 0);
    }
    // quantize epilogue: q = clamp(round((m+3)*QSCALE), 0, 255) -> u8
    // D layout (m89-verified): col = rc, row = g*4 + r
#pragma unroll
    for (int r = 0; r < 4; ++r) {
        float q = (acc[r] + 3.0f) * QSCALE + 0.5f;
        q = fminf(fmaxf(q, 0.0f), 255.0f);
        Mq[(w * 16 + g * 4 + r) * ID + rc] = (unsigned char)(unsigned int)q;
    }
    __syncthreads();  // Mq + LUT visible to all

    // ---- phase P: 4 own rows (1 uint4 each), 16 j; 4 sad + LUT gather ----
    const uint4* Mq4 = reinterpret_cast<const uint4*>(Mq);  // 1 uint4 per row
    uint4 ma[4];
#pragma unroll
    for (int r = 0; r < 4; ++r) ma[r] = Mq4[lane + 64 * r];

    float pacc[4] = {0.f, 0.f, 0.f, 0.f};
    const int j0 = w * 16;
#pragma unroll 4
    for (int j = j0; j < j0 + 16; ++j) {
        uint4 mb = Mq4[j];  // uniform addr across wave -> broadcast b128
#pragma unroll
        for (int r = 0; r < 4; ++r) {
            unsigned s = 0;
            s = sad8(ma[r].x, mb.x, s);
            s = sad8(ma[r].y, mb.y, s);
            s = sad8(ma[r].z, mb.z, s);
            s = sad8(ma[r].w, mb.w, s);
            pacc[r] += LUT[s];  // per-lane LDS gather, parallel to VALU
        }
    }
#pragma unroll
    for (int r = 0; r < 4; ++r) red[w * ND + lane + 64 * r] = pacc[r];
    __syncthreads();

    // ---- reduce + out write + concat ----
    if (t < ND) {
        float s = -1.0f;  // self-pair sad=0 -> LUT[0]=1 cancels
#pragma unroll
        for (int w2 = 0; w2 < 16; ++w2) s += red[w2 * ND + t];
        out[(size_t)t * OUT_F + IN_F + b] = s;
    } else if (t < ND + IN_F / 4) {
        const int q = t - ND;  // concat: out[b,0:512] = x[b,:] (128 float4)
        float4 v = reinterpret_cast<const float4*>(x + (size_t)b * IN_F)[q];
        reinterpret_cast<float4*>(out + (size_t)b * OUT_F)[q] = v;
    }
}

extern "C" void kernel_launch(void* const* d_in, const int* in_sizes, int n_in,
                              void* d_out, int out_size, void* d_ws, size_t ws_size,
                              hipStream_t stream) {
    const float* x = (const float*)d_in[0];
    const float* T = (const float*)d_in[1];
    float* out = (float*)d_out;
    mbd_all<<<dim3(BD), dim3(1024), 0, stream>>>(x, T, out);
}

// Round 16
// 23.655 us; speedup vs baseline: 1.0988x; 1.0988x over previous
//
#include <hip/hip_runtime.h>
#include <stdint.h>

#define IN_F 512
#define OUT_F 768
#define BD 256
#define ID 16
#define ND 256
#define CD 4096   // B*I columns in T
#define MS 20     // fallback Msh row stride

#define QSCALE 42.5f   // u8 step: range [-3,3] -> [0,255]; max SAD 4080 < 4096

typedef __bf16 bf16x8 __attribute__((ext_vector_type(8)));
typedef float f32x4 __attribute__((ext_vector_type(4)));

__device__ __forceinline__ unsigned short f2bf(float f) {
    union { float f; uint32_t u; } v; v.f = f;
    uint32_t u = v.u + 0x7FFFu + ((v.u >> 16) & 1u);  // RNE
    return (unsigned short)(u >> 16);
}

// v_sad_u8: D = sum_{k=0..3} |a.u8[k] - b.u8[k]| + c   (one full-rate VALU op)
__device__ __forceinline__ unsigned sad8(unsigned a, unsigned b, unsigned c) {
    unsigned d;
    asm("v_sad_u8 %0, %1, %2, %3" : "=v"(d) : "v"(a), "v"(b), "v"(c));
    return d;
}

// Schraudolph-style exp2 via exponent-field construction, one-sided error
// [0,+8.6%], EXACT 1.0 at s=0 (self-pair cancellation preserved).
// y = 2^(s*K), K<0:  p = (float)s * (K*2^23) + 127*2^23; y = bitcast(max(p,0))
__device__ __forceinline__ float fastexp_sad(unsigned s) {
    const float SLOPE = -1.44269504f / QSCALE * 8388608.0f;  // K * 2^23
    float p = fmaf((float)s, SLOPE, 1065353216.0f);          // 127 * 2^23
    p = fmaxf(p, 0.0f);
    union { unsigned u; float f; } v;
    v.u = (unsigned)p;
    return v.f;
}

// ---- xprep: [0,128): x -> xbf bf16 row-major; [128,256): concat copy ----
__global__ __launch_bounds__(256) void xprep_kernel(const float* __restrict__ x,
                                                    unsigned short* __restrict__ xbf,
                                                    float* __restrict__ out) {
    const int bid = blockIdx.x;
    const int t = threadIdx.x;
    if (bid < 128) {
        int i0 = (bid * 256 + t) * 8;
        float4 a = *reinterpret_cast<const float4*>(x + i0);
        float4 c = *reinterpret_cast<const float4*>(x + i0 + 4);
        union { unsigned short s[8]; uint4 v; } u;
        u.s[0] = f2bf(a.x); u.s[1] = f2bf(a.y); u.s[2] = f2bf(a.z); u.s[3] = f2bf(a.w);
        u.s[4] = f2bf(c.x); u.s[5] = f2bf(c.y); u.s[6] = f2bf(c.z); u.s[7] = f2bf(c.w);
        *reinterpret_cast<uint4*>(xbf + i0) = u.v;
    } else {
        int r = (bid - 128) * 2 + (t >> 7);
        int q = t & 127;
        float4 v = reinterpret_cast<const float4*>(x + (size_t)r * IN_F)[q];
        reinterpret_cast<float4*>(out + (size_t)r * OUT_F)[q] = v;
    }
}

// ---- fused5: one block per b, 1024 threads (16 waves). R14 G-phase +
// u8 SAD pair phase with in-register Schraudolph exp (no LDS gather).
__global__ __launch_bounds__(1024) void mbd_fused5(const unsigned short* __restrict__ xbf,
                                                   const float* __restrict__ T,
                                                   float* __restrict__ out) {
    __shared__ __align__(16) unsigned char smem[32768 + 16384 + 4096];  // 52 KB
    float* Tst = (float*)smem;                                 // 32 KB staging
    float* red = (float*)smem;                                 // reuses Tst (16 KB)
    unsigned short* Tfrag = (unsigned short*)(smem + 32768);   // 16 KB
    unsigned char* Mq = smem + 32768 + 16384;                  // u8[256][16], 4 KB

    const int b = blockIdx.x;
    const int t = threadIdx.x;
    const int lane = t & 63;
    const int w = t >> 6;
    const int rc = lane & 15;  // A-row in tile == B col (i) == D col
    const int g = lane >> 4;   // k-group

    // ---- stage T[:, b*16..+16) (512 x 16 f32 = 32 KB), coalesced ----
#pragma unroll
    for (int s = 0; s < 2; ++s) {
        int q = s * 1024 + t;
        int f = q >> 2, c4 = (q & 3) << 2;
        float4 v = *reinterpret_cast<const float4*>(T + (size_t)f * CD + b * ID + c4);
        *reinterpret_cast<float4*>(&Tst[f * ID + c4]) = v;
    }
    __syncthreads();

    // ---- convert: Tfrag[kg*128 + c*8 + e] = bf16(Tst[(kg*8+e)*16 + c]) ----
    {
        const int kg = t >> 4;
        const int c = t & 15;
        union { unsigned short s[8]; uint4 v; } p;
#pragma unroll
        for (int e = 0; e < 8; ++e) p.s[e] = f2bf(Tst[(kg * 8 + e) * ID + c]);
        *reinterpret_cast<uint4*>(Tfrag + (size_t)t * 8) = p.v;
    }
    __syncthreads();  // Tst dead from here (red reuses it after P)

    // ---- phase G: wave w -> n-tile w (16 MFMA), R13/R14-proven ----
    const bf16x8* Av = reinterpret_cast<const bf16x8*>(xbf);
    const bf16x8* Bf = reinterpret_cast<const bf16x8*>(Tfrag);
    const int arow = w * 16 + rc;
    f32x4 acc = {0.f, 0.f, 0.f, 0.f};
#pragma unroll 4
    for (int k = 0; k < 16; ++k) {
        bf16x8 afr = Av[(size_t)arow * 64 + k * 4 + g];
        bf16x8 bfr = Bf[(k * 4 + g) * 16 + rc];
        acc = __builtin_amdgcn_mfma_f32_16x16x32_bf16(afr, bfr, acc, 0, 0, 0);
    }
    // quantize epilogue: q = clamp(round((m+3)*QSCALE), 0, 255) -> u8
    // D layout (m89-verified): col = rc, row = g*4 + r
#pragma unroll
    for (int r = 0; r < 4; ++r) {
        float q = (acc[r] + 3.0f) * QSCALE + 0.5f;
        q = fminf(fmaxf(q, 0.0f), 255.0f);
        Mq[(w * 16 + g * 4 + r) * ID + rc] = (unsigned char)(unsigned int)q;
    }
    __syncthreads();  // Mq visible to all

    // ---- phase P: 4 own rows (1 uint4 each), 16 j; 4 sad + fast exp ----
    const uint4* Mq4 = reinterpret_cast<const uint4*>(Mq);  // 1 uint4 per row
    uint4 ma[4];
#pragma unroll
    for (int r = 0; r < 4; ++r) ma[r] = Mq4[lane + 64 * r];

    float pacc[4] = {0.f, 0.f, 0.f, 0.f};
    const int j0 = w * 16;
#pragma unroll 4
    for (int j = j0; j < j0 + 16; ++j) {
        uint4 mb = Mq4[j];  // uniform addr across wave -> broadcast b128
#pragma unroll
        for (int r = 0; r < 4; ++r) {
            unsigned s = 0;
            s = sad8(ma[r].x, mb.x, s);
            s = sad8(ma[r].y, mb.y, s);
            s = sad8(ma[r].z, mb.z, s);
            s = sad8(ma[r].w, mb.w, s);
            pacc[r] += fastexp_sad(s);  // pure full-rate VALU, no LDS
        }
    }
#pragma unroll
    for (int r = 0; r < 4; ++r) red[w * ND + lane + 64 * r] = pacc[r];
    __syncthreads();

    // ---- reduce + write (concat handled by xprep) ----
    if (t < ND) {
        float s = -1.0f;  // self-pair sad=0 -> exp=1.0 exactly, cancels
#pragma unroll
        for (int w2 = 0; w2 < 16; ++w2) s += red[w2 * ND + t];
        out[(size_t)t * OUT_F + IN_F + b] = s;
    }
}

// ---- fallback (ws too small): R8 single kernel (known-good ~46us) ----
__global__ __launch_bounds__(256) void mbd_one(const float* __restrict__ x,
                                               const float* __restrict__ T,
                                               float* __restrict__ out) {
    __shared__ float Tsh[IN_F * ID];
    __shared__ float Msh[ND * MS];
    const int b = blockIdx.x;
    const int t = threadIdx.x;
    const int lane = t & 63;
    const int w = t >> 6;
#pragma unroll
    for (int s = 0; s < 8; ++s) {
        int q = s * 256 + t;
        int f = q >> 2, c4 = (q & 3) << 2;
        float4 v = *reinterpret_cast<const float4*>(T + (size_t)f * CD + b * ID + c4);
        *reinterpret_cast<float4*>(&Tsh[f * ID + c4]) = v;
    }
    __syncthreads();
    const int rc = lane & 15;
    const int g = lane >> 4;
    f32x4 acc[4];
#pragma unroll
    for (int i = 0; i < 4; ++i) acc[i] = f32x4{0.f, 0.f, 0.f, 0.f};
    const float* xw = x + (size_t)(w * 64 + rc) * IN_F;
    for (int k = 0; k < 16; ++k) {
        bf16x8 bfr;
#pragma unroll
        for (int e = 0; e < 8; ++e) bfr[e] = (__bf16)Tsh[(k * 32 + g * 8 + e) * ID + rc];
        const int xo = k * 32 + g * 8;
#pragma unroll
        for (int nt = 0; nt < 4; ++nt) {
            const float* ap = xw + (size_t)nt * 16 * IN_F + xo;
            float4 a0 = *reinterpret_cast<const float4*>(ap);
            float4 a1 = *reinterpret_cast<const float4*>(ap + 4);
            bf16x8 afr;
            afr[0] = (__bf16)a0.x; afr[1] = (__bf16)a0.y;
            afr[2] = (__bf16)a0.z; afr[3] = (__bf16)a0.w;
            afr[4] = (__bf16)a1.x; afr[5] = (__bf16)a1.y;
            afr[6] = (__bf16)a1.z; afr[7] = (__bf16)a1.w;
            acc[nt] = __builtin_amdgcn_mfma_f32_16x16x32_bf16(afr, bfr, acc[nt], 0, 0, 0);
        }
    }
#pragma unroll
    for (int nt = 0; nt < 4; ++nt)
#pragma unroll
        for (int r = 0; r < 4; ++r)
            Msh[((w * 4 + nt) * 16 + g * 4 + r) * MS + rc] = acc[nt][r];
    __syncthreads();
    float mr[4][ID];
#pragma unroll
    for (int r = 0; r < 4; ++r)
#pragma unroll
        for (int ii = 0; ii < 4; ++ii) {
            float4 v = *reinterpret_cast<const float4*>(&Msh[(lane + 64 * r) * MS + ii * 4]);
            mr[r][ii * 4] = v.x; mr[r][ii * 4 + 1] = v.y;
            mr[r][ii * 4 + 2] = v.z; mr[r][ii * 4 + 3] = v.w;
        }
    float pacc[4] = {0.f, 0.f, 0.f, 0.f};
    const int j0 = w * 64;
#pragma unroll 2
    for (int j = j0; j < j0 + 64; ++j) {
        float mj[ID];
#pragma unroll
        for (int ii = 0; ii < 4; ++ii) {
            float4 v = *reinterpret_cast<const float4*>(&Msh[j * MS + ii * 4]);
            mj[ii * 4] = v.x; mj[ii * 4 + 1] = v.y;
            mj[ii * 4 + 2] = v.z; mj[ii * 4 + 3] = v.w;
        }
#pragma unroll
        for (int r = 0; r < 4; ++r) {
            float s0 = 0.f, s1 = 0.f, s2 = 0.f, s3 = 0.f;
#pragma unroll
            for (int i = 0; i < ID; i += 4) {
                s0 += fabsf(mr[r][i + 0] - mj[i + 0]);
                s1 += fabsf(mr[r][i + 1] - mj[i + 1]);
                s2 += fabsf(mr[r][i + 2] - mj[i + 2]);
                s3 += fabsf(mr[r][i + 3] - mj[i + 3]);
            }
            pacc[r] += __expf(-((s0 + s1) + (s2 + s3)));
        }
    }
    float* red = Tsh;
#pragma unroll
    for (int r = 0; r < 4; ++r) red[w * 256 + lane + 64 * r] = pacc[r];
    __syncthreads();
    {
        float s = red[t] + red[256 + t] + red[512 + t] + red[768 + t] - 1.0f;
        out[(size_t)t * OUT_F + IN_F + b] = s;
    }
    if (t < IN_F / 4) {
        float4 v = reinterpret_cast<const float4*>(x + (size_t)b * IN_F)[t];
        reinterpret_cast<float4*>(out + (size_t)b * OUT_F)[t] = v;
    }
}

extern "C" void kernel_launch(void* const* d_in, const int* in_sizes, int n_in,
                              void* d_out, int out_size, void* d_ws, size_t ws_size,
                              hipStream_t stream) {
    const float* x = (const float*)d_in[0];
    const float* T = (const float*)d_in[1];
    float* out = (float*)d_out;

    const size_t needed = (size_t)ND * IN_F * 2;  // xbf: 256 KB

    if (ws_size >= needed) {
        unsigned short* xbf = (unsigned short*)d_ws;
        xprep_kernel<<<dim3(256), dim3(256), 0, stream>>>(x, xbf, out);
        mbd_fused5<<<dim3(BD), dim3(1024), 0, stream>>>(xbf, T, out);
    } else {
        mbd_one<<<dim3(BD), dim3(256), 0, stream>>>(x, T, out);
    }
}

// Round 17
// 22.963 us; speedup vs baseline: 1.1319x; 1.0301x over previous
//
#include <hip/hip_runtime.h>
#include <stdint.h>

#define IN_F 512
#define OUT_F 768
#define BD 256
#define ID 16
#define ND 256
#define CD 4096   // B*I columns in T
#define MS 20     // fallback Msh row stride

#define QSCALE 42.5f   // u8 step: range [-3,3] -> [0,255]; max SAD 4080 < 4096

typedef __bf16 bf16x8 __attribute__((ext_vector_type(8)));
typedef float f32x4 __attribute__((ext_vector_type(4)));

__device__ __forceinline__ unsigned short f2bf(float f) {
    union { float f; uint32_t u; } v; v.f = f;
    uint32_t u = v.u + 0x7FFFu + ((v.u >> 16) & 1u);  // RNE
    return (unsigned short)(u >> 16);
}

// v_sad_u8: D = sum_{k=0..3} |a.u8[k] - b.u8[k]| + c   (one full-rate VALU op)
__device__ __forceinline__ unsigned sad8(unsigned a, unsigned b, unsigned c) {
    unsigned d;
    asm("v_sad_u8 %0, %1, %2, %3" : "=v"(d) : "v"(a), "v"(b), "v"(c));
    return d;
}

// ---- xprep: [0,128): x -> xbf bf16 row-major; [128,256): concat copy ----
__global__ __launch_bounds__(256) void xprep_kernel(const float* __restrict__ x,
                                                    unsigned short* __restrict__ xbf,
                                                    float* __restrict__ out) {
    const int bid = blockIdx.x;
    const int t = threadIdx.x;
    if (bid < 128) {
        int i0 = (bid * 256 + t) * 8;
        float4 a = *reinterpret_cast<const float4*>(x + i0);
        float4 c = *reinterpret_cast<const float4*>(x + i0 + 4);
        union { unsigned short s[8]; uint4 v; } u;
        u.s[0] = f2bf(a.x); u.s[1] = f2bf(a.y); u.s[2] = f2bf(a.z); u.s[3] = f2bf(a.w);
        u.s[4] = f2bf(c.x); u.s[5] = f2bf(c.y); u.s[6] = f2bf(c.z); u.s[7] = f2bf(c.w);
        *reinterpret_cast<uint4*>(xbf + i0) = u.v;
    } else {
        int r = (bid - 128) * 2 + (t >> 7);
        int q = t & 127;
        float4 v = reinterpret_cast<const float4*>(x + (size_t)r * IN_F)[q];
        reinterpret_cast<float4*>(out + (size_t)r * OUT_F)[q] = v;
    }
}

// ---- fused6: one block per b, 1024 threads (16 waves). R14 structure with
// A-fragment loads hoisted above the stage barriers (latency overlaps T's
// HBM stage; barrier vmcnt-drain guarantees arrival before G).
__global__ __launch_bounds__(1024) void mbd_fused6(const unsigned short* __restrict__ xbf,
                                                   const float* __restrict__ T,
                                                   float* __restrict__ out) {
    __shared__ __align__(16) unsigned char smem[32768 + 16384 + 4096];  // 52 KB
    float* Tst = (float*)smem;                                 // 32 KB staging
    float* LUT = (float*)smem;                                 // floats [0,4096) (16 KB)
    float* red = (float*)smem + 4096;                          // next 16 KB
    unsigned short* Tfrag = (unsigned short*)(smem + 32768);   // 16 KB
    unsigned char* Mq = smem + 32768 + 16384;                  // u8[256][16], 4 KB

    const int b = blockIdx.x;
    const int t = threadIdx.x;
    const int lane = t & 63;
    const int w = t >> 6;
    const int rc = lane & 15;  // A-row in tile == B col (i) == D col
    const int g = lane >> 4;   // k-group

    // ---- issue T stage loads (HBM) into registers ----
    const int q0 = t, q1 = 1024 + t;
    const int f0 = q0 >> 2, c40 = (q0 & 3) << 2;
    const int f1 = q1 >> 2, c41 = (q1 & 3) << 2;
    float4 tv0 = *reinterpret_cast<const float4*>(T + (size_t)f0 * CD + b * ID + c40);
    float4 tv1 = *reinterpret_cast<const float4*>(T + (size_t)f1 * CD + b * ID + c41);

    // ---- hoisted A-fragment loads (L2/L3): all 16 k-steps, 64 VGPR ----
    const bf16x8* Av = reinterpret_cast<const bf16x8*>(xbf);
    const int arow = w * 16 + rc;
    bf16x8 af[16];
#pragma unroll
    for (int k = 0; k < 16; ++k) af[k] = Av[(size_t)arow * 64 + k * 4 + g];

    // ---- complete T stage: write LDS (waits T loads; A stays in flight) ----
    *reinterpret_cast<float4*>(&Tst[f0 * ID + c40]) = tv0;
    *reinterpret_cast<float4*>(&Tst[f1 * ID + c41]) = tv1;
    __syncthreads();  // drains vmcnt -> A-frags also resident now

    // ---- convert: Tfrag[kg*128 + c*8 + e] = bf16(Tst[(kg*8+e)*16 + c]) ----
    {
        const int kg = t >> 4;
        const int c = t & 15;
        union { unsigned short s[8]; uint4 v; } p;
#pragma unroll
        for (int e = 0; e < 8; ++e) p.s[e] = f2bf(Tst[(kg * 8 + e) * ID + c]);
        *reinterpret_cast<uint4*>(Tfrag + (size_t)t * 8) = p.v;
    }
    __syncthreads();  // Tst dead from here; LUT overwrites it

    // ---- build exp LUT: LUT[s] = exp2(s * -log2e/QSCALE), s in [0,4096) ----
    {
        const float K = -1.44269504f / QSCALE;
#pragma unroll
        for (int u = 0; u < 4; ++u) {
            int idx = t * 4 + u;
            LUT[idx] = exp2f((float)idx * K);
        }
    }

    // ---- phase G: wave w -> n-tile w; A from registers (fully unrolled) ----
    const bf16x8* Bf = reinterpret_cast<const bf16x8*>(Tfrag);
    f32x4 acc = {0.f, 0.f, 0.f, 0.f};
#pragma unroll
    for (int k = 0; k < 16; ++k) {
        bf16x8 bfr = Bf[(k * 4 + g) * 16 + rc];  // contiguous b128, conflict-free
        acc = __builtin_amdgcn_mfma_f32_16x16x32_bf16(af[k], bfr, acc, 0, 0, 0);
    }
    // quantize epilogue: q = clamp(round((m+3)*QSCALE), 0, 255) -> u8
    // D layout (m89-verified): col = rc, row = g*4 + r
#pragma unroll
    for (int r = 0; r < 4; ++r) {
        float q = (acc[r] + 3.0f) * QSCALE + 0.5f;
        q = fminf(fmaxf(q, 0.0f), 255.0f);
        Mq[(w * 16 + g * 4 + r) * ID + rc] = (unsigned char)(unsigned int)q;
    }
    __syncthreads();  // Mq + LUT visible to all

    // ---- phase P: 4 own rows (1 uint4 each), 16 j; 4 sad + LUT gather ----
    const uint4* Mq4 = reinterpret_cast<const uint4*>(Mq);  // 1 uint4 per row
    uint4 ma[4];
#pragma unroll
    for (int r = 0; r < 4; ++r) ma[r] = Mq4[lane + 64 * r];

    float pacc[4] = {0.f, 0.f, 0.f, 0.f};
    const int j0 = w * 16;
#pragma unroll 4
    for (int j = j0; j < j0 + 16; ++j) {
        uint4 mb = Mq4[j];  // uniform addr across wave -> broadcast b128
#pragma unroll
        for (int r = 0; r < 4; ++r) {
            unsigned s = 0;
            s = sad8(ma[r].x, mb.x, s);
            s = sad8(ma[r].y, mb.y, s);
            s = sad8(ma[r].z, mb.z, s);
            s = sad8(ma[r].w, mb.w, s);
            pacc[r] += LUT[s];  // per-lane LDS gather, parallel to VALU
        }
    }
#pragma unroll
    for (int r = 0; r < 4; ++r) red[w * ND + lane + 64 * r] = pacc[r];
    __syncthreads();

    // ---- reduce + write (concat handled by xprep) ----
    if (t < ND) {
        float s = -1.0f;  // self-pair sad=0 -> LUT[0]=1 cancels
#pragma unroll
        for (int w2 = 0; w2 < 16; ++w2) s += red[w2 * ND + t];
        out[(size_t)t * OUT_F + IN_F + b] = s;
    }
}

// ---- fallback (ws too small): R8 single kernel (known-good ~46us) ----
__global__ __launch_bounds__(256) void mbd_one(const float* __restrict__ x,
                                               const float* __restrict__ T,
                                               float* __restrict__ out) {
    __shared__ float Tsh[IN_F * ID];
    __shared__ float Msh[ND * MS];
    const int b = blockIdx.x;
    const int t = threadIdx.x;
    const int lane = t & 63;
    const int w = t >> 6;
#pragma unroll
    for (int s = 0; s < 8; ++s) {
        int q = s * 256 + t;
        int f = q >> 2, c4 = (q & 3) << 2;
        float4 v = *reinterpret_cast<const float4*>(T + (size_t)f * CD + b * ID + c4);
        *reinterpret_cast<float4*>(&Tsh[f * ID + c4]) = v;
    }
    __syncthreads();
    const int rc = lane & 15;
    const int g = lane >> 4;
    f32x4 acc[4];
#pragma unroll
    for (int i = 0; i < 4; ++i) acc[i] = f32x4{0.f, 0.f, 0.f, 0.f};
    const float* xw = x + (size_t)(w * 64 + rc) * IN_F;
    for (int k = 0; k < 16; ++k) {
        bf16x8 bfr;
#pragma unroll
        for (int e = 0; e < 8; ++e) bfr[e] = (__bf16)Tsh[(k * 32 + g * 8 + e) * ID + rc];
        const int xo = k * 32 + g * 8;
#pragma unroll
        for (int nt = 0; nt < 4; ++nt) {
            const float* ap = xw + (size_t)nt * 16 * IN_F + xo;
            float4 a0 = *reinterpret_cast<const float4*>(ap);
            float4 a1 = *reinterpret_cast<const float4*>(ap + 4);
            bf16x8 afr;
            afr[0] = (__bf16)a0.x; afr[1] = (__bf16)a0.y;
            afr[2] = (__bf16)a0.z; afr[3] = (__bf16)a0.w;
            afr[4] = (__bf16)a1.x; afr[5] = (__bf16)a1.y;
            afr[6] = (__bf16)a1.z; afr[7] = (__bf16)a1.w;
            acc[nt] = __builtin_amdgcn_mfma_f32_16x16x32_bf16(afr, bfr, acc[nt], 0, 0, 0);
        }
    }
#pragma unroll
    for (int nt = 0; nt < 4; ++nt)
#pragma unroll
        for (int r = 0; r < 4; ++r)
            Msh[((w * 4 + nt) * 16 + g * 4 + r) * MS + rc] = acc[nt][r];
    __syncthreads();
    float mr[4][ID];
#pragma unroll
    for (int r = 0; r < 4; ++r)
#pragma unroll
        for (int ii = 0; ii < 4; ++ii) {
            float4 v = *reinterpret_cast<const float4*>(&Msh[(lane + 64 * r) * MS + ii * 4]);
            mr[r][ii * 4] = v.x; mr[r][ii * 4 + 1] = v.y;
            mr[r][ii * 4 + 2] = v.z; mr[r][ii * 4 + 3] = v.w;
        }
    float pacc[4] = {0.f, 0.f, 0.f, 0.f};
    const int j0 = w * 64;
#pragma unroll 2
    for (int j = j0; j < j0 + 64; ++j) {
        float mj[ID];
#pragma unroll
        for (int ii = 0; ii < 4; ++ii) {
            float4 v = *reinterpret_cast<const float4*>(&Msh[j * MS + ii * 4]);
            mj[ii * 4] = v.x; mj[ii * 4 + 1] = v.y;
            mj[ii * 4 + 2] = v.z; mj[ii * 4 + 3] = v.w;
        }
#pragma unroll
        for (int r = 0; r < 4; ++r) {
            float s0 = 0.f, s1 = 0.f, s2 = 0.f, s3 = 0.f;
#pragma unroll
            for (int i = 0; i < ID; i += 4) {
                s0 += fabsf(mr[r][i + 0] - mj[i + 0]);
                s1 += fabsf(mr[r][i + 1] - mj[i + 1]);
                s2 += fabsf(mr[r][i + 2] - mj[i + 2]);
                s3 += fabsf(mr[r][i + 3] - mj[i + 3]);
            }
            pacc[r] += __expf(-((s0 + s1) + (s2 + s3)));
        }
    }
    float* red = Tsh;
#pragma unroll
    for (int r = 0; r < 4; ++r) red[w * 256 + lane + 64 * r] = pacc[r];
    __syncthreads();
    {
        float s = red[t] + red[256 + t] + red[512 + t] + red[768 + t] - 1.0f;
        out[(size_t)t * OUT_F + IN_F + b] = s;
    }
    if (t < IN_F / 4) {
        float4 v = reinterpret_cast<const float4*>(x + (size_t)b * IN_F)[t];
        reinterpret_cast<float4*>(out + (size_t)b * OUT_F)[t] = v;
    }
}

extern "C" void kernel_launch(void* const* d_in, const int* in_sizes, int n_in,
                              void* d_out, int out_size, void* d_ws, size_t ws_size,
                              hipStream_t stream) {
    const float* x = (const float*)d_in[0];
    const float* T = (const float*)d_in[1];
    float* out = (float*)d_out;

    const size_t needed = (size_t)ND * IN_F * 2;  // xbf: 256 KB

    if (ws_size >= needed) {
        unsigned short* xbf = (unsigned short*)d_ws;
        xprep_kernel<<<dim3(256), dim3(256), 0, stream>>>(x, xbf, out);
        mbd_fused6<<<dim3(BD), dim3(1024), 0, stream>>>(xbf, T, out);
    } else {
        mbd_one<<<dim3(BD), dim3(256), 0, stream>>>(x, T, out);
    }
}